// Round 10
// baseline (168.287 us; speedup 1.0000x reference)
//
#include <hip/hip_runtime.h>
#include <float.h>

// Problem constants (from reference setup_inputs)
#define NS   16384   // samples
#define K1   512     // d_in
#define F    256     // n_feat
#define NC   1000    // n_classes
#define SPB  32      // samples per block
#define NTHR 512     // 8 waves
#define NBLK (NS / SPB)

// f16 split-precision MFMA plan (verified round 6, absmax 0):
//   value = hi + lo, hi = f16(v), lo = f16(v - hi)  => 2^-22 relative capture.
//   A*B ~= Ah*Bh + Ah*Bl + Al*Bh  (ll term ~2^-22 rel, dropped).
//   Pre-scale x*8, W*16, means*16: keeps lo terms f16-normal (flush-proof),
//   argmax-invariant (positive scales).
// MFMA 16x16x32 f16 layouts (HW-verified m89/m91/m120):
//   A[m][k]: m=lane&15, k=(lane>>4)*8+j
//   B[k][n]: n=lane&15, k=(lane>>4)*8+j
//   C/D:     col=lane&15, row=(lane>>4)*4+reg
// Tie-break: reference argmin takes FIRST min => lowest class index wins.
//
// Round-10: R6 body restored verbatim (R7/R8 inner-loop "improvements" both
// regressed; R9 cooperative launch failed and R8 proved launch-merging saves
// ~nothing anyway). Isolated change: epilogue zero-writes streamed into the
// phase-2 ks loop (overlap the 10.5us output tail under phase-2 compute),
// final one-hot = 32 single-dword stores. Prep merged to one kernel
// (prep-only; same frag layout).

typedef _Float16 half8 __attribute__((ext_vector_type(8)));
typedef float    float4v __attribute__((ext_vector_type(4)));

// Workspace (halves): Wh 131072 | Wl 131072 | Mh 262144 | Ml 262144 (R6 layout)
#define WH_OFF 0
#define WL_OFF 131072
#define MH_OFF 262144
#define ML_OFF (262144 + 262144)

// ---- merged prep: W and means -> swizzled f16 hi/lo fragments (R6 layout) ----
__global__ void prep_frags(const float* __restrict__ W,
                           const float* __restrict__ means,
                           _Float16* __restrict__ ws) {
    int g = blockIdx.x * blockDim.x + threadIdx.x;   // 0..49151
    if (g < 16384) {                                  // W: tile = ks*16+nt
        int lane = g & 63, tile = g >> 6;
        int ks = tile >> 4, nt = tile & 15;
        int k0 = ks * 32 + (lane >> 4) * 8;
        int n  = nt * 16 + (lane & 15);
        _Float16* dh = ws + WH_OFF + (size_t)g * 8;
        _Float16* dl = ws + WL_OFF + (size_t)g * 8;
#pragma unroll
        for (int j = 0; j < 8; ++j) {
            float v = W[(size_t)(k0 + j) * F + n] * 16.0f;
            _Float16 hi = (_Float16)v;
            dh[j] = hi;
            dl[j] = (_Float16)(v - (float)hi);
        }
    } else {                                          // means: tile = ks*64+gt
        int gm = g - 16384;
        int lane = gm & 63, tile = gm >> 6;
        int ks = tile >> 6, gt = tile & 63;
        int k0 = ks * 32 + (lane >> 4) * 8;
        int c  = gt * 16 + (lane & 15);
        _Float16* dh = ws + MH_OFF + (size_t)gm * 8;
        _Float16* dl = ws + ML_OFF + (size_t)gm * 8;
#pragma unroll
        for (int j = 0; j < 8; ++j) {
            float v = (c < NC) ? means[(size_t)c * F + k0 + j] * 16.0f : 0.0f;
            _Float16 hi = (_Float16)v;
            dh[j] = hi;
            dl[j] = (_Float16)(v - (float)hi);
        }
    }
}

#define MFMA(a, b, c) __builtin_amdgcn_mfma_f32_16x16x32_f16((a), (b), (c), 0, 0, 0)

// R6 config: LDS 47616 B, waves_per_eu(2,4) -> 2 blocks/CU, 16 waves/CU.
__attribute__((amdgpu_flat_work_group_size(NTHR, NTHR), amdgpu_waves_per_eu(2, 4)))
__global__ void fused_mfma(const float* __restrict__ x,
                           const _Float16* __restrict__ ws,
                           float* __restrict__ out) {
    __shared__ _Float16 xsh[2][32][44];   // x chunk hi, ping-pong, padded stride
    __shared__ _Float16 xsl[2][32][44];   // x chunk lo
    __shared__ _Float16 fh[32][264];      // feats hi (scaled x128), padded stride
    __shared__ _Float16 fl[32][264];      // feats lo
    __shared__ float cand_v[32][8];
    __shared__ int   cand_i[32][8];
    __shared__ int   bidx[32];

    const int tid  = threadIdx.x;
    const int lane = tid & 63;
    const int w    = tid >> 6;    // wave 0..7
    const int quad = lane >> 4;   // 0..3
    const int cl   = lane & 15;
    const int s0   = blockIdx.x * SPB;

    // staging coords: 512 threads cover 32 rows x 32 cols (2 floats each)
    const int xrow = tid >> 4;          // 0..31
    const int xc   = (tid & 15) * 2;    // 0,2,..,30

    // ================= Phase 1: feats = (8x) @ (16W), f16-split MFMA ========
    float4v acc1[2][2];   // [p = n-subtile][mt]
#pragma unroll
    for (int p = 0; p < 2; ++p)
#pragma unroll
        for (int mt = 0; mt < 2; ++mt)
            acc1[p][mt] = (float4v){0.f, 0.f, 0.f, 0.f};

    float2 xv = *reinterpret_cast<const float2*>(x + (size_t)(s0 + xrow) * K1 + xc);

    for (int ks = 0; ks < 16; ++ks) {
        const int buf = ks & 1;
        {   // convert (scale x8) and stage
            float vx = xv.x * 8.0f, vy = xv.y * 8.0f;
            _Float16 hx = (_Float16)vx, hy = (_Float16)vy;
            xsh[buf][xrow][xc]     = hx;
            xsh[buf][xrow][xc + 1] = hy;
            xsl[buf][xrow][xc]     = (_Float16)(vx - (float)hx);
            xsl[buf][xrow][xc + 1] = (_Float16)(vy - (float)hy);
        }
        __syncthreads();
        if (ks < 15)
            xv = *reinterpret_cast<const float2*>(
                x + (size_t)(s0 + xrow) * K1 + (ks + 1) * 32 + xc);

        half8 ah[2], al[2];
#pragma unroll
        for (int mt = 0; mt < 2; ++mt) {
            ah[mt] = *reinterpret_cast<const half8*>(&xsh[buf][mt * 16 + cl][quad * 8]);
            al[mt] = *reinterpret_cast<const half8*>(&xsl[buf][mt * 16 + cl][quad * 8]);
        }
#pragma unroll
        for (int p = 0; p < 2; ++p) {
            const int tile = ks * 16 + (w * 2 + p);
            half8 bh = *reinterpret_cast<const half8*>(
                ws + WH_OFF + ((size_t)tile * 64 + lane) * 8);
            half8 bl = *reinterpret_cast<const half8*>(
                ws + WL_OFF + ((size_t)tile * 64 + lane) * 8);
#pragma unroll
            for (int mt = 0; mt < 2; ++mt) {
                acc1[p][mt] = MFMA(ah[mt], bh, acc1[p][mt]);
                acc1[p][mt] = MFMA(ah[mt], bl, acc1[p][mt]);
                acc1[p][mt] = MFMA(al[mt], bh, acc1[p][mt]);
            }
        }
        // no trailing barrier: next iter writes the other buffer
    }

    // park feats (scaled x128) into LDS as f16 hi/lo
#pragma unroll
    for (int p = 0; p < 2; ++p)
#pragma unroll
        for (int mt = 0; mt < 2; ++mt)
#pragma unroll
            for (int r = 0; r < 4; ++r) {
                int srow = mt * 16 + quad * 4 + r;
                int n    = (w * 2 + p) * 16 + cl;
                float v  = acc1[p][mt][r];
                _Float16 hi = (_Float16)v;
                fh[srow][n] = hi;
                fl[srow][n] = (_Float16)(v - (float)hi);
            }
    __syncthreads();

    // ========== Phase 2: scores = feats @ means.T, f16-split MFMA ==========
    // Wave w owns class tiles w*8..w*8+7 (classes w*128..+127) for both M-tiles.
    // Early-zero: this block's 32 output rows = 8000 float4 zeros, streamed
    // 2/thread/ks-iter (stores overlap under the MFMA/L2-load stream); the
    // one-hot 1.0s are written after the argmax barrier (store->store order
    // to the same dword is guaranteed by the vmcnt drain at __syncthreads).
    float4v acc2[2][8];   // [mt][nt]
#pragma unroll
    for (int mt = 0; mt < 2; ++mt)
#pragma unroll
        for (int nt = 0; nt < 8; ++nt)
            acc2[mt][nt] = (float4v){0.f, 0.f, 0.f, 0.f};

    const float4 zero4 = make_float4(0.f, 0.f, 0.f, 0.f);

    for (int ks = 0; ks < 8; ++ks) {
        // early-zero stores first (no deps: can't perturb load->MFMA scheduling)
        {
            int q0 = ks * 1024 + tid;           // [0, 8192) over the 8 iters
            if (q0 < 8000)
                *reinterpret_cast<float4*>(
                    out + (size_t)(s0 + q0 / 250) * NC + (q0 % 250) * 4) = zero4;
            int q1 = q0 + 512;
            if (q1 < 8000)
                *reinterpret_cast<float4*>(
                    out + (size_t)(s0 + q1 / 250) * NC + (q1 % 250) * 4) = zero4;
        }

        half8 fah[2], fal[2];
#pragma unroll
        for (int mt = 0; mt < 2; ++mt) {
            fah[mt] = *reinterpret_cast<const half8*>(
                &fh[mt * 16 + cl][ks * 32 + quad * 8]);
            fal[mt] = *reinterpret_cast<const half8*>(
                &fl[mt * 16 + cl][ks * 32 + quad * 8]);
        }
#pragma unroll
        for (int nt = 0; nt < 8; ++nt) {
            const int tile = ks * 64 + (w * 8 + nt);
            half8 mh = *reinterpret_cast<const half8*>(
                ws + MH_OFF + ((size_t)tile * 64 + lane) * 8);
            half8 ml = *reinterpret_cast<const half8*>(
                ws + ML_OFF + ((size_t)tile * 64 + lane) * 8);
#pragma unroll
            for (int mt = 0; mt < 2; ++mt) {
                acc2[mt][nt] = MFMA(fah[mt], mh, acc2[mt][nt]);
                acc2[mt][nt] = MFMA(fah[mt], ml, acc2[mt][nt]);
                acc2[mt][nt] = MFMA(fal[mt], mh, acc2[mt][nt]);
            }
        }
    }

    // ---- argmax from C/D layout: row=quad*4+r, col=cl ----
#pragma unroll
    for (int mt = 0; mt < 2; ++mt)
#pragma unroll
        for (int r = 0; r < 4; ++r) {
            float v  = -FLT_MAX;
            int   ix = 0x7FFFFFFF;
#pragma unroll
            for (int nt = 0; nt < 8; ++nt) {          // ascending class order
                int c = (w * 8 + nt) * 16 + cl;
                if (c < NC) {
                    float sc = acc2[mt][nt][r];
                    if (sc > v) { v = sc; ix = c; }   // strict >: lowest wins
                }
            }
#pragma unroll
            for (int off = 1; off < 16; off <<= 1) {  // merge 16 lanes of quad
                float ov = __shfl_xor(v, off, 64);
                int   oi = __shfl_xor(ix, off, 64);
                if (ov > v || (ov == v && oi < ix)) { v = ov; ix = oi; }
            }
            if (cl == 0) {
                int srow = mt * 16 + quad * 4 + r;
                cand_v[srow][w] = v;
                cand_i[srow][w] = ix;
            }
        }
    __syncthreads();

    if (tid < 32) {   // merge 8 wave-candidates (ascending class ranges)
        float v  = cand_v[tid][0];
        int   ix = cand_i[tid][0];
#pragma unroll
        for (int q = 1; q < 8; ++q) {
            float ov = cand_v[tid][q];
            int   oi = cand_i[tid][q];
            if (ov > v || (ov == v && oi < ix)) { v = ov; ix = oi; }
        }
        bidx[tid] = ix;
    }
    __syncthreads();   // also drains the early-zero stores of all waves

    // ======= Epilogue: one-hot = 32 single-dword stores (rest pre-zeroed) ====
    if (tid < SPB)
        out[(size_t)(s0 + tid) * NC + bidx[tid]] = 1.0f;
}

extern "C" void kernel_launch(void* const* d_in, const int* in_sizes, int n_in,
                              void* d_out, int out_size, void* d_ws, size_t ws_size,
                              hipStream_t stream) {
    const float* x     = (const float*)d_in[0];
    const float* W     = (const float*)d_in[1];
    const float* means = (const float*)d_in[2];
    float* out         = (float*)d_out;
    _Float16* ws       = (_Float16*)d_ws;   // 1.5 MB swizzled f16 fragments

    prep_frags<<<192, 256, 0, stream>>>(W, means, ws);
    fused_mfma<<<NBLK, NTHR, 0, stream>>>(x, ws, out);
}

// Round 11
// 137.965 us; speedup vs baseline: 1.2198x; 1.2198x over previous
//
#include <hip/hip_runtime.h>
#include <float.h>

// Problem constants (from reference setup_inputs)
#define NS   16384   // samples
#define K1   512     // d_in
#define F    256     // n_feat
#define NC   1000    // n_classes
#define SPB  32      // samples per block
#define NTHR 512     // 8 waves
#define NBLK (NS / SPB)

// f16 split-precision MFMA plan (verified round 6, absmax 0):
//   value = hi + lo, hi = f16(v), lo = f16(v - hi)  => 2^-22 relative capture.
//   A*B ~= Ah*Bh + Ah*Bl + Al*Bh  (ll term ~2^-22 rel, dropped).
//   Pre-scale x*8, W*16, means*16: keeps lo terms f16-normal (flush-proof),
//   argmax-invariant (positive scales).
// MFMA 16x16x32 f16 layouts (HW-verified m89/m91/m120):
//   A[m][k]: m=lane&15, k=(lane>>4)*8+j
//   B[k][n]: n=lane&15, k=(lane>>4)*8+j
//   C/D:     col=lane&15, row=(lane>>4)*4+reg
// Tie-break: reference argmin takes FIRST min => lowest class index wins.
//
// Round-11: BYTE-EXACT ROUND-6 REVERT + one guard. Post-mortem across
// R7/R8/R10: every fused-kernel edit pushed arch-VGPR 64 -> 68; with the
// 64-AGPR accumulator (unified file) that is combined 128 -> 132, crossing
// the 4->3 waves/EU tier => ~30 us regression each time, regardless of the
// edit's content. The ONLY delta vs R6 here: amdgpu_waves_per_eu (2,4) ->
// (4,4), pinning the allocator to the <=128-combined tier R6 hit naturally.
// DO NOT add VGPR-consuming code to the fused kernel without re-checking
// VGPR_Count == 64.

typedef _Float16 half8 __attribute__((ext_vector_type(8)));
typedef float    float4v __attribute__((ext_vector_type(4)));

// Workspace layout in halves (_Float16):
//   Wh_swz: 256 tiles(ks*16+nt) * 64 lanes * 8 = 131072
//   Wl_swz: 131072
//   Mh_swz: 512 tiles(ks*64+gt) * 64 lanes * 8 = 262144
//   Ml_swz: 262144        total = 786432 halves = 1.5 MB
#define WH_OFF 0
#define WL_OFF 131072
#define MH_OFF 262144
#define ML_OFF (262144 + 262144)

// ---- prep: W[512][256] -> swizzled f16 hi/lo fragments (scale 16) ----
__global__ void prep_w(const float* __restrict__ W, _Float16* __restrict__ ws) {
    int g    = blockIdx.x * blockDim.x + threadIdx.x;  // 0..16383
    int lane = g & 63, tile = g >> 6;                  // tile = ks*16+nt
    int ks = tile >> 4, nt = tile & 15;
    int k0 = ks * 32 + (lane >> 4) * 8;
    int n  = nt * 16 + (lane & 15);
    _Float16 h[8], l[8];
#pragma unroll
    for (int j = 0; j < 8; ++j) {
        float v = W[(size_t)(k0 + j) * F + n] * 16.0f;
        _Float16 hi = (_Float16)v;
        h[j] = hi;
        l[j] = (_Float16)(v - (float)hi);
    }
    _Float16* dh = ws + WH_OFF + (size_t)g * 8;
    _Float16* dl = ws + WL_OFF + (size_t)g * 8;
#pragma unroll
    for (int j = 0; j < 8; ++j) { dh[j] = h[j]; dl[j] = l[j]; }
}

// ---- prep: means[1000][256] -> swizzled f16 hi/lo, zero-pad c>=NC, scale 16 ----
__global__ void prep_m(const float* __restrict__ means, _Float16* __restrict__ ws) {
    int g    = blockIdx.x * blockDim.x + threadIdx.x;  // 0..32767
    int lane = g & 63, tile = g >> 6;                  // tile = ks*64+gt
    int ks = tile >> 6, gt = tile & 63;
    int k0 = ks * 32 + (lane >> 4) * 8;
    int c  = gt * 16 + (lane & 15);
    _Float16 h[8], l[8];
#pragma unroll
    for (int j = 0; j < 8; ++j) {
        float v = (c < NC) ? means[(size_t)c * F + k0 + j] * 16.0f : 0.0f;
        _Float16 hi = (_Float16)v;
        h[j] = hi;
        l[j] = (_Float16)(v - (float)hi);
    }
    _Float16* dh = ws + MH_OFF + (size_t)g * 8;
    _Float16* dl = ws + ML_OFF + (size_t)g * 8;
#pragma unroll
    for (int j = 0; j < 8; ++j) { dh[j] = h[j]; dl[j] = l[j]; }
}

#define MFMA(a, b, c) __builtin_amdgcn_mfma_f32_16x16x32_f16((a), (b), (c), 0, 0, 0)

// LDS 47616 B. waves_per_eu(4,4): pin combined regs <= 128 (see header note).
__attribute__((amdgpu_flat_work_group_size(NTHR, NTHR), amdgpu_waves_per_eu(4, 4)))
__global__ void fused_mfma(const float* __restrict__ x,
                           const _Float16* __restrict__ ws,
                           float* __restrict__ out) {
    __shared__ _Float16 xsh[2][32][44];   // x chunk hi, ping-pong, padded stride
    __shared__ _Float16 xsl[2][32][44];   // x chunk lo
    __shared__ _Float16 fh[32][264];      // feats hi (scaled x128), padded stride
    __shared__ _Float16 fl[32][264];      // feats lo
    __shared__ float cand_v[32][8];
    __shared__ int   cand_i[32][8];
    __shared__ int   bidx[32];

    const int tid  = threadIdx.x;
    const int lane = tid & 63;
    const int w    = tid >> 6;    // wave 0..7
    const int quad = lane >> 4;   // 0..3
    const int cl   = lane & 15;
    const int s0   = blockIdx.x * SPB;

    // staging coords: 512 threads cover 32 rows x 32 cols (2 floats each)
    const int xrow = tid >> 4;          // 0..31
    const int xc   = (tid & 15) * 2;    // 0,2,..,30

    // ================= Phase 1: feats = (8x) @ (16W), f16-split MFMA ========
    float4v acc1[2][2];   // [p = n-subtile][mt]
#pragma unroll
    for (int p = 0; p < 2; ++p)
#pragma unroll
        for (int mt = 0; mt < 2; ++mt)
            acc1[p][mt] = (float4v){0.f, 0.f, 0.f, 0.f};

    float2 xv = *reinterpret_cast<const float2*>(x + (size_t)(s0 + xrow) * K1 + xc);

    for (int ks = 0; ks < 16; ++ks) {
        const int buf = ks & 1;
        {   // convert (scale x8) and stage
            float vx = xv.x * 8.0f, vy = xv.y * 8.0f;
            _Float16 hx = (_Float16)vx, hy = (_Float16)vy;
            xsh[buf][xrow][xc]     = hx;
            xsh[buf][xrow][xc + 1] = hy;
            xsl[buf][xrow][xc]     = (_Float16)(vx - (float)hx);
            xsl[buf][xrow][xc + 1] = (_Float16)(vy - (float)hy);
        }
        __syncthreads();
        if (ks < 15)
            xv = *reinterpret_cast<const float2*>(
                x + (size_t)(s0 + xrow) * K1 + (ks + 1) * 32 + xc);

        half8 ah[2], al[2];
#pragma unroll
        for (int mt = 0; mt < 2; ++mt) {
            ah[mt] = *reinterpret_cast<const half8*>(&xsh[buf][mt * 16 + cl][quad * 8]);
            al[mt] = *reinterpret_cast<const half8*>(&xsl[buf][mt * 16 + cl][quad * 8]);
        }
#pragma unroll
        for (int p = 0; p < 2; ++p) {
            const int tile = ks * 16 + (w * 2 + p);
            half8 bh = *reinterpret_cast<const half8*>(
                ws + WH_OFF + ((size_t)tile * 64 + lane) * 8);
            half8 bl = *reinterpret_cast<const half8*>(
                ws + WL_OFF + ((size_t)tile * 64 + lane) * 8);
#pragma unroll
            for (int mt = 0; mt < 2; ++mt) {
                acc1[p][mt] = MFMA(ah[mt], bh, acc1[p][mt]);
                acc1[p][mt] = MFMA(ah[mt], bl, acc1[p][mt]);
                acc1[p][mt] = MFMA(al[mt], bh, acc1[p][mt]);
            }
        }
        // no trailing barrier: next iter writes the other buffer
    }

    // park feats (scaled x128) into LDS as f16 hi/lo
#pragma unroll
    for (int p = 0; p < 2; ++p)
#pragma unroll
        for (int mt = 0; mt < 2; ++mt)
#pragma unroll
            for (int r = 0; r < 4; ++r) {
                int srow = mt * 16 + quad * 4 + r;
                int n    = (w * 2 + p) * 16 + cl;
                float v  = acc1[p][mt][r];
                _Float16 hi = (_Float16)v;
                fh[srow][n] = hi;
                fl[srow][n] = (_Float16)(v - (float)hi);
            }
    __syncthreads();

    // ========== Phase 2: scores = feats @ means.T, f16-split MFMA ==========
    // Wave w owns class tiles gt = w*8..w*8+7 (classes w*128..w*128+127),
    // for BOTH M-tiles => B-frag read once, 6 MFMAs per frag pair.
    float4v acc2[2][8];   // [mt][nt]
#pragma unroll
    for (int mt = 0; mt < 2; ++mt)
#pragma unroll
        for (int nt = 0; nt < 8; ++nt)
            acc2[mt][nt] = (float4v){0.f, 0.f, 0.f, 0.f};

    for (int ks = 0; ks < 8; ++ks) {
        half8 fah[2], fal[2];
#pragma unroll
        for (int mt = 0; mt < 2; ++mt) {
            fah[mt] = *reinterpret_cast<const half8*>(
                &fh[mt * 16 + cl][ks * 32 + quad * 8]);
            fal[mt] = *reinterpret_cast<const half8*>(
                &fl[mt * 16 + cl][ks * 32 + quad * 8]);
        }
#pragma unroll
        for (int nt = 0; nt < 8; ++nt) {
            const int tile = ks * 64 + (w * 8 + nt);
            half8 mh = *reinterpret_cast<const half8*>(
                ws + MH_OFF + ((size_t)tile * 64 + lane) * 8);
            half8 ml = *reinterpret_cast<const half8*>(
                ws + ML_OFF + ((size_t)tile * 64 + lane) * 8);
#pragma unroll
            for (int mt = 0; mt < 2; ++mt) {
                acc2[mt][nt] = MFMA(fah[mt], mh, acc2[mt][nt]);
                acc2[mt][nt] = MFMA(fah[mt], ml, acc2[mt][nt]);
                acc2[mt][nt] = MFMA(fal[mt], mh, acc2[mt][nt]);
            }
        }
    }

    // ---- argmax from C/D layout: row=quad*4+r, col=cl ----
#pragma unroll
    for (int mt = 0; mt < 2; ++mt)
#pragma unroll
        for (int r = 0; r < 4; ++r) {
            float v  = -FLT_MAX;
            int   ix = 0x7FFFFFFF;
#pragma unroll
            for (int nt = 0; nt < 8; ++nt) {          // ascending class order
                int c = (w * 8 + nt) * 16 + cl;
                if (c < NC) {
                    float sc = acc2[mt][nt][r];
                    if (sc > v) { v = sc; ix = c; }   // strict >: lowest wins
                }
            }
            // merge across the 16 lanes of this quad (they hold cl=0..15)
#pragma unroll
            for (int off = 1; off < 16; off <<= 1) {
                float ov = __shfl_xor(v, off, 64);
                int   oi = __shfl_xor(ix, off, 64);
                if (ov > v || (ov == v && oi < ix)) { v = ov; ix = oi; }
            }
            if (cl == 0) {
                int srow = mt * 16 + quad * 4 + r;
                cand_v[srow][w] = v;
                cand_i[srow][w] = ix;
            }
        }
    __syncthreads();

    if (tid < 32) {   // merge the 8 wave-candidates, ascending class ranges
        float v  = cand_v[tid][0];
        int   ix = cand_i[tid][0];
#pragma unroll
        for (int q = 1; q < 8; ++q) {
            float ov = cand_v[tid][q];
            int   oi = cand_i[tid][q];
            if (ov > v || (ov == v && oi < ix)) { v = ov; ix = oi; }
        }
        bidx[tid] = ix;
    }
    __syncthreads();

    // ================= Epilogue: write one-hot rows =================
    const int NF4 = NC / 4;  // 250 float4 per row
    for (int q = tid; q < SPB * NF4; q += NTHR) {
        int row   = q / NF4;
        int c4    = q - row * NF4;
        int b     = bidx[row];
        int cbase = c4 * 4;
        float4 v;
        v.x = (cbase + 0 == b) ? 1.f : 0.f;
        v.y = (cbase + 1 == b) ? 1.f : 0.f;
        v.z = (cbase + 2 == b) ? 1.f : 0.f;
        v.w = (cbase + 3 == b) ? 1.f : 0.f;
        *reinterpret_cast<float4*>(out + (size_t)(s0 + row) * NC + cbase) = v;
    }
}

extern "C" void kernel_launch(void* const* d_in, const int* in_sizes, int n_in,
                              void* d_out, int out_size, void* d_ws, size_t ws_size,
                              hipStream_t stream) {
    const float* x     = (const float*)d_in[0];
    const float* W     = (const float*)d_in[1];
    const float* means = (const float*)d_in[2];
    float* out         = (float*)d_out;
    _Float16* ws       = (_Float16*)d_ws;   // 1.5 MB of swizzled f16 fragments

    prep_w<<<64, 256, 0, stream>>>(W, ws);
    prep_m<<<128, 256, 0, stream>>>(means, ws);
    fused_mfma<<<NBLK, NTHR, 0, stream>>>(x, ws, out);
}